// Round 1
// baseline (225.559 us; speedup 1.0000x reference)
//
#include <hip/hip_runtime.h>
#include <math.h>

#define B_NUM 4
#define S_LEN 2048
#define D_DIM 1024
#define H_NUM 16
#define W_DIM 64
#define NT    (D_DIM / 64)   // 16 K-tiles of BK=64

typedef float4 f4;
typedef _Float16 f16;
typedef f16 f16x8 __attribute__((ext_vector_type(8)));
typedef f16 f16x4 __attribute__((ext_vector_type(4)));
typedef float floatx4 __attribute__((ext_vector_type(4)));

#define GLOAD_LDS16(gp, lp)                                                     \
    __builtin_amdgcn_global_load_lds(                                           \
        (const __attribute__((address_space(1))) void*)(gp),                    \
        (__attribute__((address_space(3))) void*)(lp), 16, 0, 0)

// ---------------------------------------------------------------------------
// Pre-pass 0: per-batch mask compaction. kept = (mask==0). Builds
//   fwdmap[b][jc] = original key index t (pads -> 0, a valid row)
//   cnt[b*4+0] = count, +1 = pad64 (attn), +2 = pad128, +3 = pad256 (gemm grid)
// Masked keys contribute exp(-10000)==0 -> skipping them is exact.
// ---------------------------------------------------------------------------
__global__ __launch_bounds__(256) void compact_kernel(
    const int* __restrict__ mask, short* __restrict__ fwdmap,
    int* __restrict__ cnt)
{
    __shared__ int sc[256];
    const int b   = blockIdx.x;
    const int tid = threadIdx.x;
    const int t0  = tid * 8;

#pragma unroll
    for (int j = 0; j < 8; ++j) fwdmap[b * S_LEN + t0 + j] = 0;  // pad default

    int kept[8], c = 0;
#pragma unroll
    for (int j = 0; j < 8; ++j) {
        kept[j] = (mask[b * S_LEN + t0 + j] == 0);
        c += kept[j];
    }
    sc[tid] = c;
    __syncthreads();
    for (int off = 1; off < 256; off <<= 1) {
        int add = (tid >= off) ? sc[tid - off] : 0;
        __syncthreads();
        sc[tid] += add;
        __syncthreads();
    }
    int base = sc[tid] - c;
#pragma unroll
    for (int j = 0; j < 8; ++j)
        if (kept[j]) fwdmap[b * S_LEN + (base++)] = (short)(t0 + j);
    if (tid == 255) {
        cnt[b * 4 + 0] = sc[255];
        cnt[b * 4 + 1] = (sc[255] + 63) & ~63;
        cnt[b * 4 + 2] = (sc[255] + 127) & ~127;
        cnt[b * 4 + 3] = (sc[255] + 255) & ~255;
    }
}

// ---------------------------------------------------------------------------
// Pre-pass 1: cast x -> f16.
// ---------------------------------------------------------------------------
__global__ __launch_bounds__(256) void cast_x_kernel(
    const float* __restrict__ x, f16* __restrict__ x16)
{
    const size_t i = (size_t)blockIdx.x * 256 + threadIdx.x;
    f4 t = *(const f4*)&x[i * 4];
    f16x4 o;
    o[0] = (f16)t.x; o[1] = (f16)t.y; o[2] = (f16)t.z; o[3] = (f16)t.w;
    *(f16x4*)&x16[i * 4] = o;
}

// ---------------------------------------------------------------------------
// Pre-pass 2: W[k][n] fp32 -> W^T[n][k] f16.
// ---------------------------------------------------------------------------
__global__ __launch_bounds__(256) void transpose_w_kernel(
    const float* __restrict__ Wq, const float* __restrict__ Wk,
    const float* __restrict__ Wv, f16* __restrict__ wt16)
{
    __shared__ float ts[64][68];

    const int tid = threadIdx.x;
    const int k0 = blockIdx.x * 64;
    const int n0 = blockIdx.y * 64;
    const float* Wsel = (blockIdx.z == 0) ? Wq : (blockIdx.z == 1) ? Wk : Wv;
    f16* outp = wt16 + (size_t)blockIdx.z * D_DIM * D_DIM;

    const int r  = tid >> 4;
    const int c4 = (tid & 15) * 4;
#pragma unroll
    for (int i = 0; i < 4; ++i) {
        f4 t = *(const f4*)&Wsel[(size_t)(k0 + r + i * 16) * D_DIM + n0 + c4];
        *(f4*)&ts[r + i * 16][c4] = t;
    }
    __syncthreads();
#pragma unroll
    for (int i = 0; i < 4; ++i) {
        int idx = tid + i * 256;
        int nl = idx >> 4;
        int k4 = (idx & 15) * 4;
        f16x4 o;
#pragma unroll
        for (int j = 0; j < 4; ++j) o[j] = (f16)ts[k4 + j][nl];
        *(f16x4*)&outp[(size_t)(n0 + nl) * D_DIM + k0 + k4] = o;
    }
}

// ---------------------------------------------------------------------------
// QKV GEMM: 256x256 tile, BK=64, 8 waves (2 wm x 4 wn), double-buffered LDS
// (2 x 64 KB), 4-phase-per-K-tile schedule with counted vmcnt (T3+T4) and
// setprio around the MFMA clusters (T5). XOR-swizzled LDS rows (proven
// conflict-free in the previous version: SQ_LDS_BANK_CONFLICT == 0).
//
// Per-wave frags: rows m*32+wm*16 (m=0..7), cols n*64+wn*16 (n=0..3), so the
// phase quadrants consume CONTIGUOUS 128-row LDS parts:
//   A-p0 = rows 0..127   (read only in phase 1, kept in regs for phase 2)
//   B-p0 = rows 0..127   (read only in phase 1, kept for phase 3)
//   B-p1 = rows 128..255 (read phase 2, kept for phase 4)
//   A-p1 = rows 128..255 (read phase 3, kept for phase 4)
// Phase MFMA quadrants: ph1 = m0-3 x n0-1, ph2 = m0-3 x n2-3,
//                       ph3 = m4-7 x n0-1, ph4 = m4-7 x n2-3.
// Stage schedule (1 part = 2 global_load_lds per phase):
//   ph1 of tile t stages A-p1(t+1)   [dest freed at t-1's ph3]
//   ph2 stages A-p0(t+2)             [freed by this tile's ph1]
//   ph3 stages B-p0(t+2)             [freed by ph1]
//   ph4 stages B-p1(t+2)             [freed by ph2]
// Ledger: every part's stage -> first-read gap >= 6 phases; vmcnt(8)
// (2 loads/phase, in-order retire) guarantees stages <= P-4 have landed --
// one phase of safety margin. Tail: staged K-tile index clamps to NT-1
// (rewrites identical bytes or a dead buffer -- benign; keeps the per-phase
// load count uniform so the vmcnt arithmetic holds).
//
// Grid (32 m-tiles, 12 nt) with m-tile fastest: blocks on one XCD share a
// few A-panels (L2-resident). K/V m-tiles run over COMPACTED rows via
// fwdmap gather on the per-lane global source addresses.
//   Q -> (B,H,S,W) * 0.125 ; K -> (B,H,jc,W) ; V -> (B,H,W,jc)
// ---------------------------------------------------------------------------

#define STAGE_A(BUF, P, KT) do {                                                \
    GLOAD_LDS16(asrc[P][0] + (size_t)(KT) * 64, &lds[BUF][0][(P)*128 + wid*8][0]);        \
    GLOAD_LDS16(asrc[P][1] + (size_t)(KT) * 64, &lds[BUF][0][(P)*128 + 64 + wid*8][0]);   \
} while (0)

#define STAGE_B(BUF, P, KT) do {                                                \
    GLOAD_LDS16(bsrc[P][0] + (size_t)(KT) * 64, &lds[BUF][1][(P)*128 + wid*8][0]);        \
    GLOAD_LDS16(bsrc[P][1] + (size_t)(KT) * 64, &lds[BUF][1][(P)*128 + 64 + wid*8][0]);   \
} while (0)

#define LDS_A(CUR, MABS, KH) \
    (*(const f16x8*)&lds[CUR][0][(MABS)*32 + wm16 + lx][(((KH)*4 + quad) ^ lx7) * 8])
#define LDS_B(CUR, NABS, KH) \
    (*(const f16x8*)&lds[CUR][1][(NABS)*64 + wn16 + lx][(((KH)*4 + quad) ^ lx7) * 8])

#define MFMA_PH(MB, NB) do {                                                    \
    __builtin_amdgcn_s_setprio(1);                                              \
    _Pragma("unroll") for (int m_ = 0; m_ < 4; ++m_)                            \
    _Pragma("unroll") for (int n_ = 0; n_ < 2; ++n_)                            \
    _Pragma("unroll") for (int kh_ = 0; kh_ < 2; ++kh_)                         \
        acc[(MB) + m_][(NB) + n_] = __builtin_amdgcn_mfma_f32_16x16x32_f16(     \
            af[m_][kh_], bf[(NB) + n_][kh_], acc[(MB) + m_][(NB) + n_], 0, 0, 0);\
    __builtin_amdgcn_s_setprio(0);                                              \
} while (0)

#define VMCNT8()  asm volatile("s_waitcnt vmcnt(8)" ::: "memory")
#define LGKM0()   do { asm volatile("s_waitcnt lgkmcnt(0)" ::: "memory");       \
                       __builtin_amdgcn_sched_barrier(0); } while (0)
#define BAR()     __builtin_amdgcn_s_barrier()

#define QKV_TILE(T, CUR, NXT) do {                                              \
    /* ---- phase 1: m0-3 x n0-1 ---- */                                        \
    _Pragma("unroll") for (int m_ = 0; m_ < 4; ++m_) {                          \
        af[m_][0] = LDS_A(CUR, m_, 0); af[m_][1] = LDS_A(CUR, m_, 1); }         \
    _Pragma("unroll") for (int n_ = 0; n_ < 2; ++n_) {                          \
        bf[n_][0] = LDS_B(CUR, n_, 0); bf[n_][1] = LDS_B(CUR, n_, 1); }         \
    { int kt = ((T) + 1 < NT) ? (T) + 1 : NT - 1; STAGE_A(NXT, 1, kt); }        \
    VMCNT8(); BAR(); LGKM0();                                                   \
    MFMA_PH(0, 0);                                                              \
    BAR();                                                                      \
    /* ---- phase 2: m0-3 x n2-3 ---- */                                        \
    _Pragma("unroll") for (int n_ = 0; n_ < 2; ++n_) {                          \
        bf[2 + n_][0] = LDS_B(CUR, 2 + n_, 0); bf[2 + n_][1] = LDS_B(CUR, 2 + n_, 1); } \
    { int kt = ((T) + 2 < NT) ? (T) + 2 : NT - 1; STAGE_A(CUR, 0, kt); }        \
    VMCNT8(); BAR(); LGKM0();                                                   \
    MFMA_PH(0, 2);                                                              \
    BAR();                                                                      \
    /* ---- phase 3: m4-7 x n0-1 ---- */                                        \
    _Pragma("unroll") for (int m_ = 0; m_ < 4; ++m_) {                          \
        af[m_][0] = LDS_A(CUR, 4 + m_, 0); af[m_][1] = LDS_A(CUR, 4 + m_, 1); } \
    { int kt = ((T) + 2 < NT) ? (T) + 2 : NT - 1; STAGE_B(CUR, 0, kt); }        \
    VMCNT8(); BAR(); LGKM0();                                                   \
    MFMA_PH(4, 0);                                                              \
    BAR();                                                                      \
    /* ---- phase 4: m4-7 x n2-3 (all operands already in regs) ---- */         \
    { int kt = ((T) + 2 < NT) ? (T) + 2 : NT - 1; STAGE_B(CUR, 1, kt); }        \
    VMCNT8(); BAR();                                                            \
    __builtin_amdgcn_sched_barrier(0);                                          \
    MFMA_PH(4, 2);                                                              \
    BAR();                                                                      \
} while (0)

__global__ __launch_bounds__(512, 2) void qkv_mfma_kernel(
    const f16* __restrict__ x16, const f16* __restrict__ wt16,
    const float* __restrict__ bq, const float* __restrict__ bk,
    const float* __restrict__ bv, const short* __restrict__ fwdmap,
    const int* __restrict__ cnt,
    f16* __restrict__ Qo, f16* __restrict__ Ko, f16* __restrict__ Vo)
{
    __shared__ f16 lds[2][2][256][64];   // [buf][A/B][row][k]  = 128 KiB

    const int tid  = threadIdx.x;
    const int lane = tid & 63;
    const int wid  = tid >> 6;           // 0..7
    const int lx   = lane & 15;
    const int quad = lane >> 4;
    const int lx7  = lx & 7;
    const int wm   = wid >> 2;           // 0..1
    const int wn   = wid & 3;            // 0..3
    const int wm16 = wm * 16;
    const int wn16 = wn * 16;

    const int mtile = blockIdx.x;        // 0..31 (fast dim -> XCD A-panel locality)
    const int nt    = blockIdx.y;        // 0..11
    const int midx  = nt >> 2;           // 0=Q 1=K 2=V
    const int c0    = (nt & 3) * 256;
    const int r0    = mtile * 256;
    const int bB    = r0 >> 11;          // batch (256 | 2048 -> no straddle)
    const int r0loc = r0 & (S_LEN - 1);

    if (midx > 0 && r0loc >= cnt[bB * 4 + 3]) return;   // block-uniform exit

    // Per-thread staging addresses. Stage instruction covers 8 rows x 128 B;
    // lane -> row base + (lane>>3), source k-chunk ((lane&7) ^ (row&7)) * 8
    // (row bases are multiples of 8, so row&7 == lane>>3).
    const int srow8 = lane >> 3;
    const int scw   = ((lane & 7) ^ srow8) * 8;

    const f16* asrc[2][2];
    const f16* bsrc[2][2];
#pragma unroll
    for (int p = 0; p < 2; ++p)
#pragma unroll
        for (int r = 0; r < 2; ++r) {
            int lrow = p * 128 + r * 64 + wid * 8 + srow8;
            int ar = (midx == 0)
                ? (r0 + lrow)
                : (bB * S_LEN + (int)fwdmap[bB * S_LEN + r0loc + lrow]);
            asrc[p][r] = x16 + (size_t)ar * D_DIM + scw;
            bsrc[p][r] = wt16 + (size_t)midx * D_DIM * D_DIM
                              + (size_t)(c0 + lrow) * D_DIM + scw;
        }

    floatx4 acc[8][4];
#pragma unroll
    for (int m = 0; m < 8; ++m)
#pragma unroll
        for (int n = 0; n < 4; ++n) {
            acc[m][n][0] = 0.f; acc[m][n][1] = 0.f;
            acc[m][n][2] = 0.f; acc[m][n][3] = 0.f;
        }

    f16x8 af[4][2];
    f16x8 bf[4][2];

    // Prologue: tile 0 fully + tile 1's A-p0/B-p0/B-p1 (A-p1(1) staged at t=0 ph1).
    STAGE_A(0, 0, 0); STAGE_A(0, 1, 0); STAGE_B(0, 0, 0); STAGE_B(0, 1, 0);
    STAGE_A(1, 0, 1); STAGE_B(1, 0, 1); STAGE_B(1, 1, 1);
    asm volatile("s_waitcnt vmcnt(0)" ::: "memory");
    BAR();

    for (int tt = 0; tt < NT; tt += 2) {
        QKV_TILE(tt,     0, 1);
        QKV_TILE(tt + 1, 1, 0);
    }

    asm volatile("s_waitcnt vmcnt(0)" ::: "memory");  // drain leftover clamped stages

    const float* bp = (midx == 0) ? bq : (midx == 1) ? bk : bv;
    float bias[4];
#pragma unroll
    for (int n = 0; n < 4; ++n)
        bias[n] = bp[c0 + n * 64 + wn16 + lx];

    if (midx == 0) {
#pragma unroll
        for (int m = 0; m < 8; ++m) {
            int s = r0loc + m * 32 + wm16 + quad * 4;
#pragma unroll
            for (int n = 0; n < 4; ++n) {
                int gc = c0 + n * 64 + wn16 + lx;
                int h = gc >> 6, w = gc & 63;
                size_t base = (((size_t)(bB * H_NUM + h)) * S_LEN + s) * W_DIM + w;
#pragma unroll
                for (int rr = 0; rr < 4; ++rr)
                    Qo[base + (size_t)rr * W_DIM] =
                        (f16)((acc[m][n][rr] + bias[n]) * 0.125f);
            }
        }
    } else if (midx == 1) {
#pragma unroll
        for (int m = 0; m < 8; ++m) {
            int jc = r0loc + m * 32 + wm16 + quad * 4;
#pragma unroll
            for (int n = 0; n < 4; ++n) {
                int gc = c0 + n * 64 + wn16 + lx;
                int h = gc >> 6, w = gc & 63;
                size_t base = (((size_t)(bB * H_NUM + h)) * S_LEN + jc) * W_DIM + w;
#pragma unroll
                for (int rr = 0; rr < 4; ++rr)
                    Ko[base + (size_t)rr * W_DIM] = (f16)(acc[m][n][rr] + bias[n]);
            }
        }
    } else {
#pragma unroll
        for (int m = 0; m < 8; ++m) {
            int jc = r0loc + m * 32 + wm16 + quad * 4;
#pragma unroll
            for (int n = 0; n < 4; ++n) {
                int gc = c0 + n * 64 + wn16 + lx;
                int h = gc >> 6, w = gc & 63;
                f16x4 v;
#pragma unroll
                for (int rr = 0; rr < 4; ++rr) v[rr] = (f16)(acc[m][n][rr] + bias[n]);
                *(f16x4*)&Vo[(((size_t)(bB * H_NUM + h)) * W_DIM + w) * S_LEN + jc] = v;
            }
        }
    }
}

// ---------------------------------------------------------------------------
// Flash attention over COMPACTED keys, S^T formulation, 2 q-tiles per wave.
// Unchanged this round (next optimization target once its counters surface).
// ---------------------------------------------------------------------------
#define LSTR 72

__global__ __launch_bounds__(256) void attn_kernel(
    const f16* __restrict__ Q, const f16* __restrict__ Kc,
    const f16* __restrict__ Vct, const int* __restrict__ cnt,
    float* __restrict__ out)
{
    __shared__ f16 Ks[64][LSTR];      // [jc][k]
    __shared__ f16 Vs[64][LSTR];      // [w][jc]

    const int tid  = threadIdx.x;
    const int lane = tid & 63;
    const int wid  = tid >> 6;
    const int lx   = lane & 15;
    const int quad = lane >> 4;
    const int qt = blockIdx.x, h = blockIdx.y, bb = blockIdx.z;

    const int count = cnt[bb * 4 + 0];
    const int scp   = cnt[bb * 4 + 1];

    const size_t hoff = ((size_t)(bb * H_NUM + h)) * S_LEN * W_DIM;
    const f16* Qg = Q + hoff + (size_t)qt * 128 * W_DIM;
    const f16* Kg = Kc + hoff;
    const f16* Vg = Vct + hoff;

    f16x8 qb[2][2];
#pragma unroll
    for (int u = 0; u < 2; ++u) {
        int qrow = u * 64 + wid * 16 + lx;
        qb[u][0] = *(const f16x8*)&Qg[(size_t)qrow * W_DIM + quad * 8];
        qb[u][1] = *(const f16x8*)&Qg[(size_t)qrow * W_DIM + 32 + quad * 8];
    }

    floatx4 o[2][4];
    float lsum[2] = {0.f, 0.f};
#pragma unroll
    for (int u = 0; u < 2; ++u)
#pragma unroll
        for (int wb = 0; wb < 4; ++wb) { o[u][wb][0]=0.f; o[u][wb][1]=0.f; o[u][wb][2]=0.f; o[u][wb][3]=0.f; }

    for (int k0 = 0; k0 < scp; k0 += 64) {
        __syncthreads();
#pragma unroll
        for (int it = 0; it < 2; ++it) {
            int idx = tid + it * 256;
            int row = idx >> 3, c8 = (idx & 7) * 8;
            *(f16x8*)&Ks[row][c8] = *(const f16x8*)&Kg[(size_t)(k0 + row) * W_DIM + c8];
            *(f16x8*)&Vs[row][c8] = *(const f16x8*)&Vg[(size_t)row * S_LEN + k0 + c8];
        }
        __syncthreads();

        const bool tail = (k0 + 64 > count);

        f16x4 pb[2][4];
#pragma unroll
        for (int n = 0; n < 4; ++n) {
            f16x8 ka0 = *(const f16x8*)&Ks[n * 16 + lx][quad * 8];
            f16x8 ka1 = *(const f16x8*)&Ks[n * 16 + lx][32 + quad * 8];
            const int kb = k0 + n * 16 + quad * 4;
#pragma unroll
            for (int u = 0; u < 2; ++u) {
                floatx4 s; s[0]=0.f; s[1]=0.f; s[2]=0.f; s[3]=0.f;
                s = __builtin_amdgcn_mfma_f32_16x16x32_f16(ka0, qb[u][0], s, 0, 0, 0);
                s = __builtin_amdgcn_mfma_f32_16x16x32_f16(ka1, qb[u][1], s, 0, 0, 0);
                float p[4], ls = 0.f;
                if (tail) {
#pragma unroll
                    for (int r = 0; r < 4; ++r) {
                        float sv = (kb + r < count) ? s[r] : -1.0e4f;
                        p[r] = __expf(sv); ls += p[r];
                    }
                } else {
#pragma unroll
                    for (int r = 0; r < 4; ++r) { p[r] = __expf(s[r]); ls += p[r]; }
                }
                lsum[u] += ls;
#pragma unroll
                for (int r = 0; r < 4; ++r) pb[u][n][r] = (f16)p[r];
            }
        }

#pragma unroll
        for (int wb = 0; wb < 4; ++wb) {
#pragma unroll
            for (int n = 0; n < 4; ++n) {
                f16x4 va = *(const f16x4*)&Vs[wb * 16 + lx][n * 16 + quad * 4];
#pragma unroll
                for (int u = 0; u < 2; ++u)
                    o[u][wb] = __builtin_amdgcn_mfma_f32_16x16x16f16(va, pb[u][n], o[u][wb], 0, 0, 0);
            }
        }
    }

#pragma unroll
    for (int u = 0; u < 2; ++u) {
        float ls = lsum[u];
        ls += __shfl_xor(ls, 16);
        ls += __shfl_xor(ls, 32);
        const float rl = 1.0f / ls;
        const int q = qt * 128 + u * 64 + wid * 16 + lx;
        const size_t base = ((size_t)bb * S_LEN + q) * D_DIM + h * W_DIM;
#pragma unroll
        for (int wb = 0; wb < 4; ++wb) {
            f4 r;
            r.x = o[u][wb][0] * rl;
            r.y = o[u][wb][1] * rl;
            r.z = o[u][wb][2] * rl;
            r.w = o[u][wb][3] * rl;
            *(f4*)&out[base + wb * 16 + quad * 4] = r;
        }
    }
}

// ---------------------------------------------------------------------------
extern "C" void kernel_launch(void* const* d_in, const int* in_sizes, int n_in,
                              void* d_out, int out_size, void* d_ws, size_t ws_size,
                              hipStream_t stream)
{
    const float* x    = (const float*)d_in[0];
    const float* Wq   = (const float*)d_in[1];
    const float* bq   = (const float*)d_in[2];
    const float* Wk   = (const float*)d_in[3];
    const float* bk   = (const float*)d_in[4];
    const float* Wv   = (const float*)d_in[5];
    const float* bv   = (const float*)d_in[6];
    const int*   mask = (const int*)d_in[7];
    float* out = (float*)d_out;

    const size_t per = (size_t)B_NUM * H_NUM * S_LEN * W_DIM;  // 8,388,608
    f16*   Q      = (f16*)d_ws;
    f16*   Kc     = Q + per;
    f16*   Vct    = Kc + per;
    f16*   x16    = Vct + per;
    f16*   wt16   = x16 + (size_t)(B_NUM * S_LEN) * D_DIM;
    int*   cnt    = (int*)(wt16 + (size_t)3 * D_DIM * D_DIM);
    short* fwdmap = (short*)(cnt + 4 * B_NUM);

    compact_kernel<<<B_NUM, 256, 0, stream>>>(mask, fwdmap, cnt);
    cast_x_kernel<<<(B_NUM * S_LEN * D_DIM) / 1024, 256, 0, stream>>>(x, x16);
    transpose_w_kernel<<<dim3(16, 16, 3), 256, 0, stream>>>(Wq, Wk, Wv, wt16);
    qkv_mfma_kernel<<<dim3(32, 12), 512, 0, stream>>>(
        x16, wt16, bq, bk, bv, fwdmap, cnt, Q, Kc, Vct);
    attn_kernel<<<dim3(S_LEN / 128, H_NUM, B_NUM), 256, 0, stream>>>(
        Q, Kc, Vct, cnt, out);
}